// Round 7
// baseline (831.442 us; speedup 1.0000x reference)
//
#include <hip/hip_runtime.h>
#include <stdint.h>

typedef short    v8s  __attribute__((ext_vector_type(8)));
typedef float    v4f  __attribute__((ext_vector_type(4)));
typedef unsigned short u16x8 __attribute__((ext_vector_type(8)));
typedef unsigned short ushort_t;

#define NB   32
#define NN   1024
#define CD   896
#define GD   384
#define HD   256
#define OD   1280
#define SP   1028   // LDS score pitch (floats): p/4 odd -> conflict-floor b128 reads

static __device__ __forceinline__ unsigned short f2bf(float f) {
    union { float f; unsigned u; } v; v.f = f;
    unsigned r = v.u + 0x7fffu + ((v.u >> 16) & 1u);
    return (unsigned short)(r >> 16);
}

static __device__ __forceinline__ v4f mfma16(v8s a, v8s b, v4f c) {
    return __builtin_amdgcn_mfma_f32_16x16x32_bf16(a, b, c, 0, 0, 0);
}

// ---- reg-staged tile pieces (for double-buffered proj) ----------------------
struct ARegs { float4 f[4]; };          // 16 fp32 = 64 B
struct BRegs { u16x8 h[2]; };           // 16 bf16 = 32 B

static __device__ __forceinline__ void load_a(ARegs& r, const float* __restrict__ src) {
    const float4* s4 = (const float4*)src;
    r.f[0] = s4[0]; r.f[1] = s4[1]; r.f[2] = s4[2]; r.f[3] = s4[3];
}
static __device__ __forceinline__ void store_a(ushort_t* dst, const ARegs& r) {
    u16x8 p0, p1;
    p0[0]=f2bf(r.f[0].x); p0[1]=f2bf(r.f[0].y); p0[2]=f2bf(r.f[0].z); p0[3]=f2bf(r.f[0].w);
    p0[4]=f2bf(r.f[1].x); p0[5]=f2bf(r.f[1].y); p0[6]=f2bf(r.f[1].z); p0[7]=f2bf(r.f[1].w);
    p1[0]=f2bf(r.f[2].x); p1[1]=f2bf(r.f[2].y); p1[2]=f2bf(r.f[2].z); p1[3]=f2bf(r.f[2].w);
    p1[4]=f2bf(r.f[3].x); p1[5]=f2bf(r.f[3].y); p1[6]=f2bf(r.f[3].z); p1[7]=f2bf(r.f[3].w);
    *(u16x8*)dst = p0;
    *(u16x8*)(dst + 8) = p1;
}
static __device__ __forceinline__ void load_b(BRegs& r, const ushort_t* __restrict__ src) {
    const u16x8* s = (const u16x8*)src;
    r.h[0] = s[0]; r.h[1] = s[1];
}
static __device__ __forceinline__ void store_b(ushort_t* dst, const BRegs& r) {
    *(u16x8*)dst = r.h[0];
    *(u16x8*)(dst + 8) = r.h[1];
}

// ---------------- weight transpose+convert (merged Wq+Wk): f32 -> bf16^T ----
__global__ void convw2_kernel(const float* __restrict__ Wq, ushort_t* __restrict__ Wqt,
                              const float* __restrict__ Wk, ushort_t* __restrict__ Wkt) {
    int bx = blockIdx.x;
    if (bx < CD) {
        int idx = bx * 256 + threadIdx.x;
        int k = idx >> 8, n = idx & 255;
        Wqt[(size_t)n * CD + k] = f2bf(Wq[idx]);
    } else {
        int idx = (bx - CD) * 256 + threadIdx.x;
        int k = idx >> 8, n = idx & 255;
        Wkt[(size_t)n * GD + k] = f2bf(Wk[idx]);
    }
}

__global__ void zero_kernel(float* __restrict__ p, int n) {
    int i = blockIdx.x * 256 + threadIdx.x;
    if (i < n) p[i] = 0.f;
}

// ---------------- cluster pooled mean: 1024 blocks (32 rows each), 4-acc ILP
__global__ void pool_kernel(const float* __restrict__ cf, float* __restrict__ pooled) {
    int b = blockIdx.y, chunk = blockIdx.x, t = threadIdx.x;
    if (t >= 224) return;                          // 224 float4 = 896 floats
    const float4* p = (const float4*)(cf + (size_t)(b * NN + chunk * 32) * CD) + t;
    float4 s0{0,0,0,0}, s1{0,0,0,0}, s2{0,0,0,0}, s3{0,0,0,0};
    #pragma unroll 1
    for (int n = 0; n < 32; n += 4) {
        float4 v0 = p[(size_t)(n + 0) * 224];
        float4 v1 = p[(size_t)(n + 1) * 224];
        float4 v2 = p[(size_t)(n + 2) * 224];
        float4 v3 = p[(size_t)(n + 3) * 224];
        s0.x += v0.x; s0.y += v0.y; s0.z += v0.z; s0.w += v0.w;
        s1.x += v1.x; s1.y += v1.y; s1.z += v1.z; s1.w += v1.w;
        s2.x += v2.x; s2.y += v2.y; s2.z += v2.z; s2.w += v2.w;
        s3.x += v3.x; s3.y += v3.y; s3.z += v3.z; s3.w += v3.w;
    }
    const float sc = 1.f / 1024.f;
    float* dst = pooled + b * CD + t * 4;
    atomicAdd(dst + 0, (s0.x + s1.x + s2.x + s3.x) * sc);
    atomicAdd(dst + 1, (s0.y + s1.y + s2.y + s3.y) * sc);
    atomicAdd(dst + 2, (s0.z + s1.z + s2.z + s3.z) * sc);
    atomicAdd(dst + 3, (s0.w + s1.w + s2.w + s3.w) * sc);
}

// ---------------- projection GEMM: C_bf16[M,256] = A_f32[M,KD] @ Wt^T + bias
// Single N-pass, 128x256 tile, 512 threads, double-buffered LDS: next tile's
// global loads issue BEFORE the MFMA phase -> HBM latency hides under MFMA
// (grid=256 -> 1 block/CU, no cross-block overlap to rely on).
template<int KD>
__global__ __launch_bounds__(512) void proj_kernel(
    const float* __restrict__ A, const ushort_t* __restrict__ Wt,
    const float* __restrict__ bias, ushort_t* __restrict__ C)
{
    __shared__ ushort_t lA[2][128 * 40];
    __shared__ ushort_t lB[2][256 * 40];
    const int tid  = threadIdx.x;
    const int m0   = blockIdx.x * 128;
    const int lane = tid & 63, wave = tid >> 6;
    const int l15  = lane & 15, quad = lane >> 4;
    const int wrow = (wave >> 2) * 64, wcol = (wave & 3) * 64;
    const int srow = tid >> 1, shalf = tid & 1;    // B rows 0..255; A rows 0..127 (tid<256)
    const int KT   = KD / 32;

    v4f acc[4][4];
    #pragma unroll
    for (int i = 0; i < 4; ++i)
        #pragma unroll
        for (int j = 0; j < 4; ++j) acc[i][j] = v4f{0.f, 0.f, 0.f, 0.f};

    ARegs ar; BRegs br;
    // prologue: stage kt=0
    if (tid < 256) {
        load_a(ar, A + (size_t)(m0 + srow) * KD + shalf * 16);
        store_a(&lA[0][srow * 40 + shalf * 16], ar);
    }
    load_b(br, Wt + (size_t)srow * KD + shalf * 16);
    store_b(&lB[0][srow * 40 + shalf * 16], br);
    __syncthreads();

    for (int kt = 0; kt < KT; ++kt) {
        const int p = kt & 1;
        // issue next tile's global loads (latency hides under MFMA below)
        if (kt + 1 < KT) {
            if (tid < 256)
                load_a(ar, A + (size_t)(m0 + srow) * KD + (kt + 1) * 32 + shalf * 16);
            load_b(br, Wt + (size_t)srow * KD + (kt + 1) * 32 + shalf * 16);
        }
        v8s af[4], bfr[4];
        #pragma unroll
        for (int rt = 0; rt < 4; ++rt) af[rt]  = *(const v8s*)&lA[p][(wrow + rt * 16 + l15) * 40 + quad * 8];
        #pragma unroll
        for (int ct = 0; ct < 4; ++ct) bfr[ct] = *(const v8s*)&lB[p][(wcol + ct * 16 + l15) * 40 + quad * 8];
        #pragma unroll
        for (int rt = 0; rt < 4; ++rt)
            #pragma unroll
            for (int ct = 0; ct < 4; ++ct)
                acc[rt][ct] = mfma16(af[rt], bfr[ct], acc[rt][ct]);
        __syncthreads();               // all waves done reading buf[p^1] from prev write target
        if (kt + 1 < KT) {
            if (tid < 256)
                store_a(&lA[p ^ 1][srow * 40 + shalf * 16], ar);
            store_b(&lB[p ^ 1][srow * 40 + shalf * 16], br);
        }
        __syncthreads();               // staged data visible before next MFMA phase
    }

    #pragma unroll
    for (int ct = 0; ct < 4; ++ct) {
        int col = wcol + ct * 16 + l15;
        float bv = bias[col];
        #pragma unroll
        for (int rt = 0; rt < 4; ++rt)
            #pragma unroll
            for (int r = 0; r < 4; ++r) {
                int row = m0 + wrow + rt * 16 + quad * 4 + r;
                C[(size_t)row * 256 + col] = f2bf(acc[rt][ct][r] + bv);
            }
    }
}

// ---------------- fused attention: QK^T + log(w) -> softmax -> attn + colsum
// Block: 512 threads (8 waves), owns M=32 rows of one batch, full N=1024.
// LDS: S[32][SP] fp32 = 131.6 KB -> 1 block/CU. (Proven optimum; 16-row and
// register-resident variants both measured slower.)
// Launched as TWO 16-batch dispatches (bat0=0,16): perf-neutral split so the
// rocprof top-5 ceiling drops to ~63us and hidden kernels can surface.
__global__ __launch_bounds__(512) void attn_kernel(
    const ushort_t* __restrict__ Qb, const ushort_t* __restrict__ Kb,
    const float* __restrict__ cw,
    float* __restrict__ attn, float* __restrict__ colsum, int bat0)
{
    __shared__ float S[32 * SP];
    const int bat = bat0 + blockIdx.x;   // batch on x -> batch%8 pins to XCD (K L2 reuse)
    const int m0  = blockIdx.y * 32;
    const int tid = threadIdx.x;
    const int lane = tid & 63, wave = tid >> 6;
    const int l15 = lane & 15, quad = lane >> 4;

    // ---- Phase 1: S[m][n] = scale*Q@K^T + log(w+1e-8), wave handles 128 cols
    v8s af[2][8];
    #pragma unroll
    for (int rt = 0; rt < 2; ++rt)
        #pragma unroll
        for (int ks = 0; ks < 8; ++ks)
            af[rt][ks] = *(const v8s*)(Qb + (size_t)(bat * NN + m0 + rt * 16 + l15) * HD + ks * 32 + quad * 8);

    const int n0w = wave * 128;
    #pragma unroll 2
    for (int ct = 0; ct < 8; ++ct) {
        const int col = n0w + ct * 16 + l15;
        v8s bfr[8];
        #pragma unroll
        for (int ks = 0; ks < 8; ++ks)
            bfr[ks] = *(const v8s*)(Kb + (size_t)(bat * NN + col) * HD + ks * 32 + quad * 8);
        // prefetch cw for this tile
        float w0[4], w1[4];
        const size_t cwb = ((size_t)bat << 20) + col;
        #pragma unroll
        for (int r = 0; r < 4; ++r) {
            w0[r] = cw[cwb + (size_t)(m0 + quad * 4 + r) * NN];
            w1[r] = cw[cwb + (size_t)(m0 + 16 + quad * 4 + r) * NN];
        }
        v4f acc0 = {0.f, 0.f, 0.f, 0.f}, acc1 = {0.f, 0.f, 0.f, 0.f};
        #pragma unroll
        for (int ks = 0; ks < 8; ++ks) {
            acc0 = mfma16(af[0][ks], bfr[ks], acc0);
            acc1 = mfma16(af[1][ks], bfr[ks], acc1);
        }
        #pragma unroll
        for (int r = 0; r < 4; ++r) {
            const int row0 = quad * 4 + r;
            S[row0 * SP + col]        = acc0[r] * 0.0625f + __logf(w0[r] + 1e-8f);
            S[(16 + row0) * SP + col] = acc1[r] * 0.0625f + __logf(w1[r] + 1e-8f);
        }
    }
    __syncthreads();

    // ---- Phase 2: per-row softmax in LDS, write attn to global,
    //               accumulate per-column partial sums in registers
    float4 cs[4];
    #pragma unroll
    for (int i = 0; i < 4; ++i) cs[i] = float4{0.f, 0.f, 0.f, 0.f};

    #pragma unroll 1
    for (int rr = 0; rr < 4; ++rr) {
        const int row = wave * 4 + rr;
        float* Srow = &S[row * SP];
        float4 v[4];
        #pragma unroll
        for (int i = 0; i < 4; ++i) v[i] = *(float4*)(Srow + i * 256 + lane * 4);
        float m = -1e30f;
        #pragma unroll
        for (int i = 0; i < 4; ++i)
            m = fmaxf(m, fmaxf(fmaxf(v[i].x, v[i].y), fmaxf(v[i].z, v[i].w)));
        #pragma unroll
        for (int off = 1; off <= 32; off <<= 1) m = fmaxf(m, __shfl_xor(m, off));
        float s = 0.f;
        #pragma unroll
        for (int i = 0; i < 4; ++i) {
            v[i].x = __expf(v[i].x - m); v[i].y = __expf(v[i].y - m);
            v[i].z = __expf(v[i].z - m); v[i].w = __expf(v[i].w - m);
            s += v[i].x + v[i].y + v[i].z + v[i].w;
        }
        #pragma unroll
        for (int off = 1; off <= 32; off <<= 1) s += __shfl_xor(s, off);
        const float inv = 1.0f / s;
        float* grow = attn + ((size_t)bat << 20) + (size_t)(m0 + row) * NN;
        #pragma unroll
        for (int i = 0; i < 4; ++i) {
            v[i].x *= inv; v[i].y *= inv; v[i].z *= inv; v[i].w *= inv;
            *(float4*)(grow + i * 256 + lane * 4) = v[i];
            cs[i].x += v[i].x; cs[i].y += v[i].y; cs[i].z += v[i].z; cs[i].w += v[i].w;
        }
    }

    // ---- Phase 3: cross-wave colsum reduce (reuse S[0..8191] as [8][1024])
    __syncthreads();                     // all waves done reading their S rows
    #pragma unroll
    for (int i = 0; i < 4; ++i)
        *(float4*)&S[wave * 1024 + i * 256 + lane * 4] = cs[i];
    __syncthreads();
    {
        const int c = tid * 2;           // 512 threads x 2 cols = 1024
        float s0 = 0.f, s1 = 0.f;
        #pragma unroll
        for (int w = 0; w < 8; ++w) {
            float2 p = *(const float2*)&S[w * 1024 + c];
            s0 += p.x; s1 += p.y;
        }
        atomicAdd(&colsum[(size_t)bat * NN + c + 0], s0);
        atomicAdd(&colsum[(size_t)bat * NN + c + 1], s1);
    }
}

// ---------------- weighted gf pooling: gws[b,:] = (1/N) colsum[b,:] @ gf[b] -
__global__ __launch_bounds__(192) void wpool_kernel(
    const float* __restrict__ gf, const float* __restrict__ colsum,
    float* __restrict__ gws)
{
    const int b = blockIdx.y, m0 = blockIdx.x * 128, t = threadIdx.x;
    const float2* base = (const float2*)(gf + (size_t)(b * NN + m0) * GD);
    const float* wbase = colsum + (size_t)b * NN + m0;
    float sx = 0.f, sy = 0.f;
    #pragma unroll 4
    for (int m = 0; m < 128; ++m) {
        const float w = wbase[m] * (1.f / 1024.f);
        float2 v = base[(size_t)m * (GD / 2) + t];
        sx += w * v.x; sy += w * v.y;
    }
    atomicAdd(&gws[b * GD + 2 * t + 0], sx);
    atomicAdd(&gws[b * GD + 2 * t + 1], sy);
}

// ---------------- tiny V projection: gpool[b,d] = gws[b,:] @ Wv[:,d] + bv[d] -
__global__ __launch_bounds__(256) void vproj_kernel(
    const float* __restrict__ gws, const float* __restrict__ Wv,
    const float* __restrict__ bv, float* __restrict__ gpool)
{
    const int b = blockIdx.x, d = threadIdx.x;
    const float* g = gws + (size_t)b * GD;
    float acc = bv[d];
    #pragma unroll 8
    for (int k = 0; k < GD; ++k) acc += g[k] * Wv[(size_t)k * HD + d];
    gpool[b * HD + d] = acc;
}

// ---------------- tails: k-split for 1&2; tail3 folds BN+ReLU, plain write --
__global__ void tail1_kernel(const float* __restrict__ pooled, const float* __restrict__ gpool,
                             const float* __restrict__ Wcp, const float* __restrict__ bcp,
                             const float* __restrict__ Wgp, const float* __restrict__ bgp,
                             float* __restrict__ combined)
{
    int idx = blockIdx.x * 256 + threadIdx.x;  // 32*1280
    int b = idx / OD, c = idx % OD;
    int kc = blockIdx.y;                       // 0..3
    float acc = 0.f;
    if (c < 640) {
        if (kc == 0) acc = bcp[c];
        const float* a = pooled + b * CD;
        const int k0 = kc * 224;
        for (int k = k0; k < k0 + 224; ++k) acc += a[k] * Wcp[k * 640 + c];
    } else {
        int c2 = c - 640;
        if (kc == 0) acc = bgp[c2];
        const float* g = gpool + b * HD;
        const int k0 = kc * 64;
        for (int k = k0; k < k0 + 64; ++k) acc += g[k] * Wgp[k * 640 + c2];
    }
    atomicAdd(&combined[idx], acc);
}

__global__ void tail2_kernel(const float* __restrict__ combined, const float* __restrict__ Wf1,
                             const float* __restrict__ bf1, float* __restrict__ h)
{
    int idx = blockIdx.x * 256 + threadIdx.x;
    int b = idx / OD, c = idx % OD;
    int k0 = blockIdx.y * 256;                 // 5 chunks
    float acc = (blockIdx.y == 0) ? bf1[c] : 0.f;
    const float* a = combined + b * OD;
    for (int k = k0; k < k0 + 256; ++k) acc += a[k] * Wf1[k * OD + c];
    atomicAdd(&h[idx], acc);
}

// out[b,c] = sum_k relu(bn(h[b,k])) * Wf2[k,c] + bf2[c]   (BN folded on load)
__global__ void tail3_kernel(const float* __restrict__ h, const float* __restrict__ Wf2,
                             const float* __restrict__ bf2,
                             const float* __restrict__ g, const float* __restrict__ be,
                             const float* __restrict__ mn, const float* __restrict__ vr,
                             float* __restrict__ out)
{
    int idx = blockIdx.x * 256 + threadIdx.x;
    int b = idx / OD, c = idx % OD;
    const float* a = h + b * OD;
    float a0 = 0.f, a1 = 0.f, a2 = 0.f, a3 = 0.f;
    #pragma unroll 1
    for (int k = 0; k < OD; k += 4) {
        float4 av = *(const float4*)(a + k);
        float s0 = rsqrtf(vr[k + 0] + 1e-5f) * g[k + 0];
        float s1 = rsqrtf(vr[k + 1] + 1e-5f) * g[k + 1];
        float s2 = rsqrtf(vr[k + 2] + 1e-5f) * g[k + 2];
        float s3 = rsqrtf(vr[k + 3] + 1e-5f) * g[k + 3];
        float x0 = fmaxf((av.x - mn[k + 0]) * s0 + be[k + 0], 0.f);
        float x1 = fmaxf((av.y - mn[k + 1]) * s1 + be[k + 1], 0.f);
        float x2 = fmaxf((av.z - mn[k + 2]) * s2 + be[k + 2], 0.f);
        float x3 = fmaxf((av.w - mn[k + 3]) * s3 + be[k + 3], 0.f);
        a0 += x0 * Wf2[(size_t)(k + 0) * OD + c];
        a1 += x1 * Wf2[(size_t)(k + 1) * OD + c];
        a2 += x2 * Wf2[(size_t)(k + 2) * OD + c];
        a3 += x3 * Wf2[(size_t)(k + 3) * OD + c];
    }
    out[idx] = bf2[c] + (a0 + a1) + (a2 + a3);
}

// ---------------- launch ----------------------------------------------------
extern "C" void kernel_launch(void* const* d_in, const int* in_sizes, int n_in,
                              void* d_out, int out_size, void* d_ws, size_t ws_size,
                              hipStream_t stream)
{
    const float* cf  = (const float*)d_in[0];
    const float* gf  = (const float*)d_in[1];
    const float* cw  = (const float*)d_in[2];
    const float* Wq  = (const float*)d_in[3];  const float* bq  = (const float*)d_in[4];
    const float* Wk  = (const float*)d_in[5];  const float* bk  = (const float*)d_in[6];
    const float* Wv  = (const float*)d_in[7];  const float* bv  = (const float*)d_in[8];
    const float* Wcp = (const float*)d_in[9];  const float* bcp = (const float*)d_in[10];
    const float* Wgp = (const float*)d_in[11]; const float* bgp = (const float*)d_in[12];
    const float* Wf1 = (const float*)d_in[13]; const float* bf1 = (const float*)d_in[14];
    const float* bng = (const float*)d_in[15]; const float* bnb = (const float*)d_in[16];
    const float* bnm = (const float*)d_in[17]; const float* bnv = (const float*)d_in[18];
    const float* Wf2 = (const float*)d_in[19]; const float* bf2 = (const float*)d_in[20];

    float* out  = (float*)d_out;         // [32,1280]
    float* attn = out + NB * OD;         // [32,1024,1024] fp32

    char* w = (char*)d_ws;
    ushort_t* Qb  = (ushort_t*)w; w += (size_t)NB * NN * HD * 2;
    ushort_t* Kb  = (ushort_t*)w; w += (size_t)NB * NN * HD * 2;
    ushort_t* Wqt = (ushort_t*)w; w += (size_t)HD * CD * 2;
    ushort_t* Wkt = (ushort_t*)w; w += (size_t)HD * GD * 2;
    float* pooled   = (float*)w; w += (size_t)NB * CD * 4;   // zeroed together:
    float* gpool    = (float*)w; w += (size_t)NB * HD * 4;   //   pooled,gpool,
    float* colsum   = (float*)w; w += (size_t)NB * NN * 4;   //   colsum,gws,
    float* gws      = (float*)w; w += (size_t)NB * GD * 4;   //   combined,hbuf
    float* combined = (float*)w; w += (size_t)NB * OD * 4;   //   (contiguous)
    float* hbuf     = (float*)w; w += (size_t)NB * OD * 4;

    // zero pooled+gpool+colsum+gws+combined+hbuf in one pass (contiguous)
    const int nz = NB * (CD + HD + NN + GD + OD + OD);
    zero_kernel<<<dim3((nz + 255) / 256), dim3(256), 0, stream>>>(pooled, nz);
    convw2_kernel<<<dim3(CD + GD), dim3(256), 0, stream>>>(Wq, Wqt, Wk, Wkt);
    pool_kernel<<<dim3(32, 32), dim3(256), 0, stream>>>(cf, pooled);

    proj_kernel<CD><<<dim3(256), dim3(512), 0, stream>>>(cf, Wqt, bq, Qb);
    proj_kernel<GD><<<dim3(256), dim3(512), 0, stream>>>(gf, Wkt, bk, Kb);

    attn_kernel<<<dim3(16, 32), dim3(512), 0, stream>>>(Qb, Kb, cw, attn, colsum, 0);
    attn_kernel<<<dim3(16, 32), dim3(512), 0, stream>>>(Qb, Kb, cw, attn, colsum, 16);

    wpool_kernel<<<dim3(8, 32), dim3(192), 0, stream>>>(gf, colsum, gws);
    vproj_kernel<<<dim3(32), dim3(256), 0, stream>>>(gws, Wv, bv, gpool);

    tail1_kernel<<<dim3(160, 4), dim3(256), 0, stream>>>(pooled, gpool, Wcp, bcp, Wgp, bgp, combined);
    tail2_kernel<<<dim3(160, 5), dim3(256), 0, stream>>>(combined, Wf1, bf1, hbuf);
    tail3_kernel<<<dim3(160), dim3(256), 0, stream>>>(hbuf, Wf2, bf2, bng, bnb, bnm, bnv, out);
}

// Round 8
// 633.670 us; speedup vs baseline: 1.3121x; 1.3121x over previous
//
#include <hip/hip_runtime.h>
#include <stdint.h>

typedef short    v8s  __attribute__((ext_vector_type(8)));
typedef float    v4f  __attribute__((ext_vector_type(4)));
typedef unsigned short u16x8 __attribute__((ext_vector_type(8)));
typedef unsigned short ushort_t;

#define NB   32
#define NN   1024
#define CD   896
#define GD   384
#define HD   256
#define OD   1280
#define SP   1028   // LDS score pitch (floats): p/4 odd -> conflict-floor b128 reads

static __device__ __forceinline__ unsigned short f2bf(float f) {
    union { float f; unsigned u; } v; v.f = f;
    unsigned r = v.u + 0x7fffu + ((v.u >> 16) & 1u);
    return (unsigned short)(r >> 16);
}

static __device__ __forceinline__ v4f mfma16(v8s a, v8s b, v4f c) {
    return __builtin_amdgcn_mfma_f32_16x16x32_bf16(a, b, c, 0, 0, 0);
}

// ---- reg-staged tile pieces (for double-buffered proj) ----------------------
struct ARegs { float4 f[4]; };          // 16 fp32 = 64 B
struct BRegs { u16x8 h[2]; };           // 16 bf16 = 32 B

static __device__ __forceinline__ void load_a(ARegs& r, const float* __restrict__ src) {
    const float4* s4 = (const float4*)src;
    r.f[0] = s4[0]; r.f[1] = s4[1]; r.f[2] = s4[2]; r.f[3] = s4[3];
}
static __device__ __forceinline__ void store_a(ushort_t* dst, const ARegs& r) {
    u16x8 p0, p1;
    p0[0]=f2bf(r.f[0].x); p0[1]=f2bf(r.f[0].y); p0[2]=f2bf(r.f[0].z); p0[3]=f2bf(r.f[0].w);
    p0[4]=f2bf(r.f[1].x); p0[5]=f2bf(r.f[1].y); p0[6]=f2bf(r.f[1].z); p0[7]=f2bf(r.f[1].w);
    p1[0]=f2bf(r.f[2].x); p1[1]=f2bf(r.f[2].y); p1[2]=f2bf(r.f[2].z); p1[3]=f2bf(r.f[2].w);
    p1[4]=f2bf(r.f[3].x); p1[5]=f2bf(r.f[3].y); p1[6]=f2bf(r.f[3].z); p1[7]=f2bf(r.f[3].w);
    *(u16x8*)dst = p0;
    *(u16x8*)(dst + 8) = p1;
}
static __device__ __forceinline__ void load_b(BRegs& r, const ushort_t* __restrict__ src) {
    const u16x8* s = (const u16x8*)src;
    r.h[0] = s[0]; r.h[1] = s[1];
}
static __device__ __forceinline__ void store_b(ushort_t* dst, const BRegs& r) {
    *(u16x8*)dst = r.h[0];
    *(u16x8*)(dst + 8) = r.h[1];
}

// ---------------- weight transpose+convert (merged Wq+Wk): f32 -> bf16^T ----
__global__ void convw2_kernel(const float* __restrict__ Wq, ushort_t* __restrict__ Wqt,
                              const float* __restrict__ Wk, ushort_t* __restrict__ Wkt) {
    int bx = blockIdx.x;
    if (bx < CD) {
        int idx = bx * 256 + threadIdx.x;
        int k = idx >> 8, n = idx & 255;
        Wqt[(size_t)n * CD + k] = f2bf(Wq[idx]);
    } else {
        int idx = (bx - CD) * 256 + threadIdx.x;
        int k = idx >> 8, n = idx & 255;
        Wkt[(size_t)n * GD + k] = f2bf(Wk[idx]);
    }
}

__global__ void zero_kernel(float* __restrict__ p, int n) {
    int i = blockIdx.x * 256 + threadIdx.x;
    if (i < n) p[i] = 0.f;
}

// ---------------- cluster pooled mean: 1024 blocks (32 rows each), 4-acc ILP
__global__ void pool_kernel(const float* __restrict__ cf, float* __restrict__ pooled) {
    int b = blockIdx.y, chunk = blockIdx.x, t = threadIdx.x;
    if (t >= 224) return;                          // 224 float4 = 896 floats
    const float4* p = (const float4*)(cf + (size_t)(b * NN + chunk * 32) * CD) + t;
    float4 s0{0,0,0,0}, s1{0,0,0,0}, s2{0,0,0,0}, s3{0,0,0,0};
    #pragma unroll 1
    for (int n = 0; n < 32; n += 4) {
        float4 v0 = p[(size_t)(n + 0) * 224];
        float4 v1 = p[(size_t)(n + 1) * 224];
        float4 v2 = p[(size_t)(n + 2) * 224];
        float4 v3 = p[(size_t)(n + 3) * 224];
        s0.x += v0.x; s0.y += v0.y; s0.z += v0.z; s0.w += v0.w;
        s1.x += v1.x; s1.y += v1.y; s1.z += v1.z; s1.w += v1.w;
        s2.x += v2.x; s2.y += v2.y; s2.z += v2.z; s2.w += v2.w;
        s3.x += v3.x; s3.y += v3.y; s3.z += v3.z; s3.w += v3.w;
    }
    const float sc = 1.f / 1024.f;
    float* dst = pooled + b * CD + t * 4;
    atomicAdd(dst + 0, (s0.x + s1.x + s2.x + s3.x) * sc);
    atomicAdd(dst + 1, (s0.y + s1.y + s2.y + s3.y) * sc);
    atomicAdd(dst + 2, (s0.z + s1.z + s2.z + s3.z) * sc);
    atomicAdd(dst + 3, (s0.w + s1.w + s2.w + s3.w) * sc);
}

// ---------------- projection GEMM: C_bf16[M,256] = A_f32[M,KD] @ Wt^T + bias
// Single N-pass, 128x256 tile, 512 threads, double-buffered LDS (measured
// neutral-or-better vs single-buffer in R7's bundle accounting).
template<int KD>
__global__ __launch_bounds__(512) void proj_kernel(
    const float* __restrict__ A, const ushort_t* __restrict__ Wt,
    const float* __restrict__ bias, ushort_t* __restrict__ C)
{
    __shared__ ushort_t lA[2][128 * 40];
    __shared__ ushort_t lB[2][256 * 40];
    const int tid  = threadIdx.x;
    const int m0   = blockIdx.x * 128;
    const int lane = tid & 63, wave = tid >> 6;
    const int l15  = lane & 15, quad = lane >> 4;
    const int wrow = (wave >> 2) * 64, wcol = (wave & 3) * 64;
    const int srow = tid >> 1, shalf = tid & 1;    // B rows 0..255; A rows 0..127 (tid<256)
    const int KT   = KD / 32;

    v4f acc[4][4];
    #pragma unroll
    for (int i = 0; i < 4; ++i)
        #pragma unroll
        for (int j = 0; j < 4; ++j) acc[i][j] = v4f{0.f, 0.f, 0.f, 0.f};

    ARegs ar; BRegs br;
    // prologue: stage kt=0
    if (tid < 256) {
        load_a(ar, A + (size_t)(m0 + srow) * KD + shalf * 16);
        store_a(&lA[0][srow * 40 + shalf * 16], ar);
    }
    load_b(br, Wt + (size_t)srow * KD + shalf * 16);
    store_b(&lB[0][srow * 40 + shalf * 16], br);
    __syncthreads();

    for (int kt = 0; kt < KT; ++kt) {
        const int p = kt & 1;
        // issue next tile's global loads (latency hides under MFMA below)
        if (kt + 1 < KT) {
            if (tid < 256)
                load_a(ar, A + (size_t)(m0 + srow) * KD + (kt + 1) * 32 + shalf * 16);
            load_b(br, Wt + (size_t)srow * KD + (kt + 1) * 32 + shalf * 16);
        }
        v8s af[4], bfr[4];
        #pragma unroll
        for (int rt = 0; rt < 4; ++rt) af[rt]  = *(const v8s*)&lA[p][(wrow + rt * 16 + l15) * 40 + quad * 8];
        #pragma unroll
        for (int ct = 0; ct < 4; ++ct) bfr[ct] = *(const v8s*)&lB[p][(wcol + ct * 16 + l15) * 40 + quad * 8];
        #pragma unroll
        for (int rt = 0; rt < 4; ++rt)
            #pragma unroll
            for (int ct = 0; ct < 4; ++ct)
                acc[rt][ct] = mfma16(af[rt], bfr[ct], acc[rt][ct]);
        __syncthreads();               // all waves done reading buf[p^1] from prev write target
        if (kt + 1 < KT) {
            if (tid < 256)
                store_a(&lA[p ^ 1][srow * 40 + shalf * 16], ar);
            store_b(&lB[p ^ 1][srow * 40 + shalf * 16], br);
        }
        __syncthreads();               // staged data visible before next MFMA phase
    }

    #pragma unroll
    for (int ct = 0; ct < 4; ++ct) {
        int col = wcol + ct * 16 + l15;
        float bv = bias[col];
        #pragma unroll
        for (int rt = 0; rt < 4; ++rt)
            #pragma unroll
            for (int r = 0; r < 4; ++r) {
                int row = m0 + wrow + rt * 16 + quad * 4 + r;
                C[(size_t)row * 256 + col] = f2bf(acc[rt][ct][r] + bv);
            }
    }
}

// ---------------- fused attention: QK^T + log(w) -> softmax -> attn + colsum
// Block: 512 threads (8 waves), owns M=32 rows of one batch, full N=1024.
// LDS: S[32][SP] fp32 = 131.6 KB -> 1 block/CU. (Proven optimum; 16-row and
// register-resident variants both measured slower.)
// TWO 16-batch dispatches: perf-neutral (verified R7), keeps top-5 ceiling
// at ~63us so other kernels stay visible in the profile.
__global__ __launch_bounds__(512) void attn_kernel(
    const ushort_t* __restrict__ Qb, const ushort_t* __restrict__ Kb,
    const float* __restrict__ cw,
    float* __restrict__ attn, float* __restrict__ colsum, int bat0)
{
    __shared__ float S[32 * SP];
    const int bat = bat0 + blockIdx.x;   // batch on x -> batch%8 pins to XCD (K L2 reuse)
    const int m0  = blockIdx.y * 32;
    const int tid = threadIdx.x;
    const int lane = tid & 63, wave = tid >> 6;
    const int l15 = lane & 15, quad = lane >> 4;

    // ---- Phase 1: S[m][n] = scale*Q@K^T + log(w+1e-8), wave handles 128 cols
    v8s af[2][8];
    #pragma unroll
    for (int rt = 0; rt < 2; ++rt)
        #pragma unroll
        for (int ks = 0; ks < 8; ++ks)
            af[rt][ks] = *(const v8s*)(Qb + (size_t)(bat * NN + m0 + rt * 16 + l15) * HD + ks * 32 + quad * 8);

    const int n0w = wave * 128;
    #pragma unroll 2
    for (int ct = 0; ct < 8; ++ct) {
        const int col = n0w + ct * 16 + l15;
        v8s bfr[8];
        #pragma unroll
        for (int ks = 0; ks < 8; ++ks)
            bfr[ks] = *(const v8s*)(Kb + (size_t)(bat * NN + col) * HD + ks * 32 + quad * 8);
        // prefetch cw for this tile
        float w0[4], w1[4];
        const size_t cwb = ((size_t)bat << 20) + col;
        #pragma unroll
        for (int r = 0; r < 4; ++r) {
            w0[r] = cw[cwb + (size_t)(m0 + quad * 4 + r) * NN];
            w1[r] = cw[cwb + (size_t)(m0 + 16 + quad * 4 + r) * NN];
        }
        v4f acc0 = {0.f, 0.f, 0.f, 0.f}, acc1 = {0.f, 0.f, 0.f, 0.f};
        #pragma unroll
        for (int ks = 0; ks < 8; ++ks) {
            acc0 = mfma16(af[0][ks], bfr[ks], acc0);
            acc1 = mfma16(af[1][ks], bfr[ks], acc1);
        }
        #pragma unroll
        for (int r = 0; r < 4; ++r) {
            const int row0 = quad * 4 + r;
            S[row0 * SP + col]        = acc0[r] * 0.0625f + __logf(w0[r] + 1e-8f);
            S[(16 + row0) * SP + col] = acc1[r] * 0.0625f + __logf(w1[r] + 1e-8f);
        }
    }
    __syncthreads();

    // ---- Phase 2: per-row softmax in LDS, write attn to global,
    //               accumulate per-column partial sums in registers
    float4 cs[4];
    #pragma unroll
    for (int i = 0; i < 4; ++i) cs[i] = float4{0.f, 0.f, 0.f, 0.f};

    #pragma unroll 1
    for (int rr = 0; rr < 4; ++rr) {
        const int row = wave * 4 + rr;
        float* Srow = &S[row * SP];
        float4 v[4];
        #pragma unroll
        for (int i = 0; i < 4; ++i) v[i] = *(float4*)(Srow + i * 256 + lane * 4);
        float m = -1e30f;
        #pragma unroll
        for (int i = 0; i < 4; ++i)
            m = fmaxf(m, fmaxf(fmaxf(v[i].x, v[i].y), fmaxf(v[i].z, v[i].w)));
        #pragma unroll
        for (int off = 1; off <= 32; off <<= 1) m = fmaxf(m, __shfl_xor(m, off));
        float s = 0.f;
        #pragma unroll
        for (int i = 0; i < 4; ++i) {
            v[i].x = __expf(v[i].x - m); v[i].y = __expf(v[i].y - m);
            v[i].z = __expf(v[i].z - m); v[i].w = __expf(v[i].w - m);
            s += v[i].x + v[i].y + v[i].z + v[i].w;
        }
        #pragma unroll
        for (int off = 1; off <= 32; off <<= 1) s += __shfl_xor(s, off);
        const float inv = 1.0f / s;
        float* grow = attn + ((size_t)bat << 20) + (size_t)(m0 + row) * NN;
        #pragma unroll
        for (int i = 0; i < 4; ++i) {
            v[i].x *= inv; v[i].y *= inv; v[i].z *= inv; v[i].w *= inv;
            *(float4*)(grow + i * 256 + lane * 4) = v[i];
            cs[i].x += v[i].x; cs[i].y += v[i].y; cs[i].z += v[i].z; cs[i].w += v[i].w;
        }
    }

    // ---- Phase 3: cross-wave colsum reduce (reuse S[0..8191] as [8][1024])
    __syncthreads();                     // all waves done reading their S rows
    #pragma unroll
    for (int i = 0; i < 4; ++i)
        *(float4*)&S[wave * 1024 + i * 256 + lane * 4] = cs[i];
    __syncthreads();
    {
        const int c = tid * 2;           // 512 threads x 2 cols = 1024
        float s0 = 0.f, s1 = 0.f;
        #pragma unroll
        for (int w = 0; w < 8; ++w) {
            float2 p = *(const float2*)&S[w * 1024 + c];
            s0 += p.x; s1 += p.y;
        }
        atomicAdd(&colsum[(size_t)bat * NN + c + 0], s0);
        atomicAdd(&colsum[(size_t)bat * NN + c + 1], s1);
    }
}

// ---------------- weighted gf pooling: gws[b,:] = (1/N) colsum[b,:] @ gf[b] -
__global__ __launch_bounds__(192) void wpool_kernel(
    const float* __restrict__ gf, const float* __restrict__ colsum,
    float* __restrict__ gws)
{
    const int b = blockIdx.y, m0 = blockIdx.x * 128, t = threadIdx.x;
    const float2* base = (const float2*)(gf + (size_t)(b * NN + m0) * GD);
    const float* wbase = colsum + (size_t)b * NN + m0;
    float sx = 0.f, sy = 0.f;
    #pragma unroll 4
    for (int m = 0; m < 128; ++m) {
        const float w = wbase[m] * (1.f / 1024.f);
        float2 v = base[(size_t)m * (GD / 2) + t];
        sx += w * v.x; sy += w * v.y;
    }
    atomicAdd(&gws[b * GD + 2 * t + 0], sx);
    atomicAdd(&gws[b * GD + 2 * t + 1], sy);
}

// ---------------- tiny V projection: gpool[b,d] = gws[b,:] @ Wv[:,d] + bv[d] -
__global__ __launch_bounds__(256) void vproj_kernel(
    const float* __restrict__ gws, const float* __restrict__ Wv,
    const float* __restrict__ bv, float* __restrict__ gpool)
{
    const int b = blockIdx.x, d = threadIdx.x;
    const float* g = gws + (size_t)b * GD;
    float acc = bv[d];
    #pragma unroll 8
    for (int k = 0; k < GD; ++k) acc += g[k] * Wv[(size_t)k * HD + d];
    gpool[b * HD + d] = acc;
}

// ---------------- tails: deep k-split, fp32 atomicAdd, bias on chunk 0 ------
// Lesson (R7): k-split/block-count >> pass-fusion for these M=32 GEMVs. The
// fused no-split tail3 measured 181.7us (Occ 7.4%, VALUBusy 9.9%).
__global__ void tail1_kernel(const float* __restrict__ pooled, const float* __restrict__ gpool,
                             const float* __restrict__ Wcp, const float* __restrict__ bcp,
                             const float* __restrict__ Wgp, const float* __restrict__ bgp,
                             float* __restrict__ combined)
{
    int idx = blockIdx.x * 256 + threadIdx.x;  // 32*1280
    int b = idx / OD, c = idx % OD;
    int kc = blockIdx.y;                       // 0..7
    float acc = 0.f;
    if (c < 640) {
        if (kc == 0) acc = bcp[c];
        const float* a = pooled + b * CD;
        const int k0 = kc * 112;               // 896/8
        for (int k = k0; k < k0 + 112; ++k) acc += a[k] * Wcp[k * 640 + c];
    } else {
        int c2 = c - 640;
        if (kc == 0) acc = bgp[c2];
        const float* g = gpool + b * HD;
        const int k0 = kc * 32;                // 256/8
        for (int k = k0; k < k0 + 32; ++k) acc += g[k] * Wgp[k * 640 + c2];
    }
    atomicAdd(&combined[idx], acc);
}

__global__ void tail2_kernel(const float* __restrict__ combined, const float* __restrict__ Wf1,
                             const float* __restrict__ bf1, float* __restrict__ h)
{
    int idx = blockIdx.x * 256 + threadIdx.x;
    int b = idx / OD, c = idx % OD;
    int k0 = blockIdx.y * 128;                 // 10 chunks
    float acc = (blockIdx.y == 0) ? bf1[c] : 0.f;
    const float* a = combined + b * OD;
    for (int k = k0; k < k0 + 128; ++k) acc += a[k] * Wf1[k * OD + c];
    atomicAdd(&h[idx], acc);
}

__global__ void bnrelu_kernel(float* __restrict__ h,
                              const float* __restrict__ g, const float* __restrict__ be,
                              const float* __restrict__ mn, const float* __restrict__ vr)
{
    int idx = blockIdx.x * 256 + threadIdx.x;
    int c = idx % OD;
    float x = (h[idx] - mn[c]) * rsqrtf(vr[c] + 1e-5f) * g[c] + be[c];
    h[idx] = fmaxf(x, 0.f);
}

__global__ void tail3_kernel(const float* __restrict__ h, const float* __restrict__ Wf2,
                             const float* __restrict__ bf2, float* __restrict__ out)
{
    int idx = blockIdx.x * 256 + threadIdx.x;
    int b = idx / OD, c = idx % OD;
    int k0 = blockIdx.y * 128;                 // 10 chunks
    float acc = (blockIdx.y == 0) ? bf2[c] : 0.f;
    const float* a = h + b * OD;
    for (int k = k0; k < k0 + 128; ++k) acc += a[k] * Wf2[k * OD + c];
    atomicAdd(&out[idx], acc);
}

// ---------------- launch ----------------------------------------------------
extern "C" void kernel_launch(void* const* d_in, const int* in_sizes, int n_in,
                              void* d_out, int out_size, void* d_ws, size_t ws_size,
                              hipStream_t stream)
{
    const float* cf  = (const float*)d_in[0];
    const float* gf  = (const float*)d_in[1];
    const float* cw  = (const float*)d_in[2];
    const float* Wq  = (const float*)d_in[3];  const float* bq  = (const float*)d_in[4];
    const float* Wk  = (const float*)d_in[5];  const float* bk  = (const float*)d_in[6];
    const float* Wv  = (const float*)d_in[7];  const float* bv  = (const float*)d_in[8];
    const float* Wcp = (const float*)d_in[9];  const float* bcp = (const float*)d_in[10];
    const float* Wgp = (const float*)d_in[11]; const float* bgp = (const float*)d_in[12];
    const float* Wf1 = (const float*)d_in[13]; const float* bf1 = (const float*)d_in[14];
    const float* bng = (const float*)d_in[15]; const float* bnb = (const float*)d_in[16];
    const float* bnm = (const float*)d_in[17]; const float* bnv = (const float*)d_in[18];
    const float* Wf2 = (const float*)d_in[19]; const float* bf2 = (const float*)d_in[20];

    float* out  = (float*)d_out;         // [32,1280]
    float* attn = out + NB * OD;         // [32,1024,1024] fp32

    char* w = (char*)d_ws;
    ushort_t* Qb  = (ushort_t*)w; w += (size_t)NB * NN * HD * 2;
    ushort_t* Kb  = (ushort_t*)w; w += (size_t)NB * NN * HD * 2;
    ushort_t* Wqt = (ushort_t*)w; w += (size_t)HD * CD * 2;
    ushort_t* Wkt = (ushort_t*)w; w += (size_t)HD * GD * 2;
    float* pooled   = (float*)w; w += (size_t)NB * CD * 4;   // zeroed together:
    float* gpool    = (float*)w; w += (size_t)NB * HD * 4;   //   pooled,gpool,
    float* colsum   = (float*)w; w += (size_t)NB * NN * 4;   //   colsum,gws,
    float* gws      = (float*)w; w += (size_t)NB * GD * 4;   //   combined,hbuf
    float* combined = (float*)w; w += (size_t)NB * OD * 4;   //   (contiguous)
    float* hbuf     = (float*)w; w += (size_t)NB * OD * 4;

    // zero pooled+gpool+colsum+gws+combined+hbuf in one pass (contiguous)
    const int nz = NB * (CD + HD + NN + GD + OD + OD);
    zero_kernel<<<dim3((nz + 255) / 256), dim3(256), 0, stream>>>(pooled, nz);
    zero_kernel<<<dim3(160), dim3(256), 0, stream>>>(out, NB * OD);   // atomicAdd target
    convw2_kernel<<<dim3(CD + GD), dim3(256), 0, stream>>>(Wq, Wqt, Wk, Wkt);
    pool_kernel<<<dim3(32, 32), dim3(256), 0, stream>>>(cf, pooled);

    proj_kernel<CD><<<dim3(256), dim3(512), 0, stream>>>(cf, Wqt, bq, Qb);
    proj_kernel<GD><<<dim3(256), dim3(512), 0, stream>>>(gf, Wkt, bk, Kb);

    attn_kernel<<<dim3(16, 32), dim3(512), 0, stream>>>(Qb, Kb, cw, attn, colsum, 0);
    attn_kernel<<<dim3(16, 32), dim3(512), 0, stream>>>(Qb, Kb, cw, attn, colsum, 16);

    wpool_kernel<<<dim3(8, 32), dim3(192), 0, stream>>>(gf, colsum, gws);
    vproj_kernel<<<dim3(32), dim3(256), 0, stream>>>(gws, Wv, bv, gpool);

    tail1_kernel<<<dim3(160, 8), dim3(256), 0, stream>>>(pooled, gpool, Wcp, bcp, Wgp, bgp, combined);
    tail2_kernel<<<dim3(160, 10), dim3(256), 0, stream>>>(combined, Wf1, bf1, hbuf);
    bnrelu_kernel<<<dim3(160), dim3(256), 0, stream>>>(hbuf, bng, bnb, bnm, bnv);
    tail3_kernel<<<dim3(160, 10), dim3(256), 0, stream>>>(hbuf, Wf2, bf2, out);
}